// Round 10
// baseline (155.867 us; speedup 1.0000x reference)
//
#include <hip/hip_runtime.h>
#include <math.h>

#define N_NODES 10000
#define E_EDGES 320000
#define EA      (E_EDGES + N_NODES)   // 330000 with self-loops
#define IN_DIM  128
#define HID     512                    // heads*dhead = 8*64
#define HEADS   8
#define OUT_DIM 32
#define NEG     0.2f
#define CAP     160                    // dst bucket capacity (max degree ~54)
#define N_PAD   10048                  // 628*16
#define NRB     628                    // 16-row blocks
#define RB_SH   4096                   // shorts per 16-row block: 2 seg x 16 chunks x 128

// k_pre block partition (256 threads each)
#define PWB  32                        // prep_w blocks
#define PTB  64                        // W2 transpose blocks
#define ZBK  40                        // zero cnt blocks
// k_sg block partition (512 threads each)
#define SCB  645                       // scatter: ceil(EA/512)

typedef __attribute__((ext_vector_type(8))) short bf16x8;
typedef __attribute__((ext_vector_type(4))) float f32x4;

__device__ __forceinline__ float leaky(float x){ return x > 0.f ? x : NEG * x; }

__device__ __forceinline__ unsigned short bf16rn(float x){
    unsigned int b = __float_as_uint(x);
    b += 0x7fffu + ((b >> 16) & 1u);
    return (unsigned short)(b >> 16);
}

// ------------- fused prologue: prep_x | prep_w | W2 transpose | zero cnt --------
// Fragment-chunk layout per 16-row block: chunk c=(seg*16+kk8), bytes
// [(c*16+l15)*8 .. +8) shorts; stores are dense 16B uint4 per thread.
__global__ void k_pre(const float* __restrict__ x, const float* __restrict__ W1,
                      const float* __restrict__ W2, int* __restrict__ cnt,
                      unsigned short* __restrict__ Ax, unsigned short* __restrict__ Bt,
                      float* __restrict__ W2T){
    int b = blockIdx.x, t = threadIdx.x;
    if (b < NRB){
        __shared__ float xs[16 * 132];
        int rb = b;
#pragma unroll
        for (int j = 0; j < 2; j++){
            int idx = t + j * 256;             // 0..511
            int r = idx >> 5, c4 = idx & 31;
            int row = rb * 16 + r;
            float4 v = make_float4(0.f, 0.f, 0.f, 0.f);
            if (row < N_NODES)
                v = *reinterpret_cast<const float4*>(x + (size_t)row * IN_DIM + c4 * 4);
            *reinterpret_cast<float4*>(&xs[r * 132 + c4 * 4]) = v;
        }
        __syncthreads();
        int l15 = t & 15, kk8 = t >> 4;
        unsigned short hi[8], lo[8];
#pragma unroll
        for (int el = 0; el < 8; el++){
            float f = xs[l15 * 132 + kk8 * 8 + el];
            hi[el] = bf16rn(f);
            lo[el] = bf16rn(f - __uint_as_float((unsigned)hi[el] << 16));
        }
        uint4 H, L;
        H.x = hi[0] | ((unsigned)hi[1] << 16); H.y = hi[2] | ((unsigned)hi[3] << 16);
        H.z = hi[4] | ((unsigned)hi[5] << 16); H.w = hi[6] | ((unsigned)hi[7] << 16);
        L.x = lo[0] | ((unsigned)lo[1] << 16); L.y = lo[2] | ((unsigned)lo[3] << 16);
        L.z = lo[4] | ((unsigned)lo[5] << 16); L.w = lo[6] | ((unsigned)lo[7] << 16);
        unsigned short* base = Ax + (size_t)rb * RB_SH;
        *reinterpret_cast<uint4*>(base + (kk8 * 16 + l15) * 8) = H;
        *reinterpret_cast<uint4*>(base + 2048 + (kk8 * 16 + l15) * 8) = L;
    } else if (b < NRB + PWB){
        __shared__ float ws[128 * 17];
        int nb = b - NRB;
        int j = t & 15, kr = t >> 4;
#pragma unroll
        for (int it = 0; it < 8; it++){
            int k = it * 16 + kr;
            ws[k * 17 + j] = W1[(size_t)k * HID + nb * 16 + j];
        }
        __syncthreads();
        int l15 = t & 15, kk8 = t >> 4;
        unsigned short hi[8], lo[8];
#pragma unroll
        for (int el = 0; el < 8; el++){
            float f = ws[(kk8 * 8 + el) * 17 + l15];
            hi[el] = bf16rn(f);
            lo[el] = bf16rn(f - __uint_as_float((unsigned)hi[el] << 16));
        }
        uint4 H, L;
        H.x = hi[0] | ((unsigned)hi[1] << 16); H.y = hi[2] | ((unsigned)hi[3] << 16);
        H.z = hi[4] | ((unsigned)hi[5] << 16); H.w = hi[6] | ((unsigned)hi[7] << 16);
        L.x = lo[0] | ((unsigned)lo[1] << 16); L.y = lo[2] | ((unsigned)lo[3] << 16);
        L.z = lo[4] | ((unsigned)lo[5] << 16); L.w = lo[6] | ((unsigned)lo[7] << 16);
        unsigned short* base = Bt + (size_t)nb * RB_SH;
        *reinterpret_cast<uint4*>(base + (kk8 * 16 + l15) * 8) = H;
        *reinterpret_cast<uint4*>(base + 2048 + (kk8 * 16 + l15) * 8) = L;
    } else if (b < NRB + PWB + PTB){
        int idx = (b - NRB - PWB) * 256 + t;   // 16384 = 32*512
        int k = idx & 511, c = idx >> 9;
        W2T[(size_t)c * HID + k] = W2[(size_t)k * OUT_DIM + c];
    } else {
        int i = (b - NRB - PWB - PTB) * 256 + t;
        if (i < N_NODES) cnt[i] = 0;
    }
}

// --------- fused: bucket scatter || layer-1 MFMA GEMM (1 rb x 8 heads/block) ----
// Split GEMM: x@W = xhi·whi + xlo·whi + xhi·wlo (double-bf16, fp32-grade).
__launch_bounds__(512)
__global__ void k_sg(const int* __restrict__ eidx, int* __restrict__ cnt,
                     int* __restrict__ esrc,
                     const unsigned short* __restrict__ Ax,
                     const unsigned short* __restrict__ Bt,
                     const float* __restrict__ a1s, const float* __restrict__ a1d,
                     unsigned short* __restrict__ h1,
                     float* __restrict__ as1, float* __restrict__ ad1){
    if (blockIdx.x < SCB){
        int e = blockIdx.x * 512 + threadIdx.x;
        if (e < EA){
            int d, s;
            if (e < E_EDGES){ s = eidx[e]; d = eidx[E_EDGES + e]; }
            else { s = d = e - E_EDGES; }
            int pos = atomicAdd(&cnt[d], 1);
            if (pos < CAP) esrc[d * CAP + pos] = s;
        }
        return;
    }
    int rb = blockIdx.x - SCB;                 // 0..627
    int by = threadIdx.x >> 6;                 // wave = head
    int lane = threadIdx.x & 63;
    int l15 = lane & 15, grp = lane >> 4;
    int m0 = rb * 16;
    int n0 = by * 64;
    const unsigned short* ap = Ax + (size_t)rb * RB_SH + (size_t)lane * 8;
    bf16x8 a_hi[4], a_lo[4];
#pragma unroll
    for (int ks = 0; ks < 4; ks++){
        a_hi[ks] = *reinterpret_cast<const bf16x8*>(ap + ks * 512);
        a_lo[ks] = *reinterpret_cast<const bf16x8*>(ap + 2048 + ks * 512);
    }
    const unsigned short* bp = Bt + (size_t)(by * 4) * RB_SH + (size_t)lane * 8;
    f32x4 acc[4] = {};
#pragma unroll
    for (int ks = 0; ks < 4; ks++){
#pragma unroll
        for (int ns = 0; ns < 4; ns++){
            const unsigned short* bb = bp + (size_t)ns * RB_SH + ks * 512;
            bf16x8 b_hi = *reinterpret_cast<const bf16x8*>(bb);
            bf16x8 b_lo = *reinterpret_cast<const bf16x8*>(bb + 2048);
            acc[ns] = __builtin_amdgcn_mfma_f32_16x16x32_bf16(a_hi[ks], b_hi, acc[ns], 0, 0, 0);
            acc[ns] = __builtin_amdgcn_mfma_f32_16x16x32_bf16(a_lo[ks], b_hi, acc[ns], 0, 0, 0);
            acc[ns] = __builtin_amdgcn_mfma_f32_16x16x32_bf16(a_hi[ks], b_lo, acc[ns], 0, 0, 0);
        }
    }
    float vs[4] = {0.f, 0.f, 0.f, 0.f}, vd[4] = {0.f, 0.f, 0.f, 0.f};
#pragma unroll
    for (int ns = 0; ns < 4; ns++){
        int c = n0 + ns * 16 + l15;
        float a_s = a1s[c], a_d = a1d[c];
#pragma unroll
        for (int r = 0; r < 4; r++){
            float v = acc[ns][r];
            int rr = m0 + grp * 4 + r;
            if (rr < N_NODES) h1[(size_t)rr * HID + c] = bf16rn(v);
            vs[r] += v * a_s; vd[r] += v * a_d;
        }
    }
#pragma unroll
    for (int r = 0; r < 4; r++){
#pragma unroll
        for (int off = 8; off >= 1; off >>= 1){
            vs[r] += __shfl_xor(vs[r], off);
            vd[r] += __shfl_xor(vd[r], off);
        }
    }
    if (l15 == 0){
#pragma unroll
        for (int r = 0; r < 4; r++){
            int rr = m0 + grp * 4 + r;
            if (rr < N_NODES){ as1[rr * HEADS + by] = vs[r]; ad1[rr * HEADS + by] = vd[r]; }
        }
    }
}

// ------- layer 1: softmax + aggregate + bias + ELU + FUSED layer-2 GEMM row ------
// one block (128 threads) per dst node. Phase B: 4-way unrolled gather.
// Epilogue: h2[n] = elu_row @ W2 via LDS row + W2T; h1b never hits memory.
__launch_bounds__(128)
__global__ void k_agg1(const unsigned short* __restrict__ h1,
                       const float* __restrict__ as1, const float* __restrict__ ad1,
                       const int* __restrict__ cnt, const int* __restrict__ esrc,
                       const float* __restrict__ b1, const float* __restrict__ W2T,
                       const float* __restrict__ a2s, const float* __restrict__ a2d,
                       float* __restrict__ h2, float* __restrict__ vs2,
                       float* __restrict__ vd2){
    int n = blockIdx.x;
    int c = cnt[n]; if (c > CAP) c = CAP;
    int beg = n * CAP;
    int t = threadIdx.x;
    __shared__ int   s_src[CAP];
    __shared__ float s_w[HEADS][CAP + 1];
    __shared__ float s_adn[HEADS];
    __shared__ float s_red[2][HEADS];
    __shared__ float s_m[HEADS];
    __shared__ float s_row[HID];
    __shared__ float s_p[4][OUT_DIM];
    if (t < HEADS) s_adn[t] = ad1[n * HEADS + t];
    __syncthreads();
    float pm[HEADS];
#pragma unroll
    for (int h = 0; h < HEADS; h++) pm[h] = -INFINITY;
    for (int i = t; i < c; i += 128){
        int s = esrc[beg + i];
        float4 alo = *reinterpret_cast<const float4*>(as1 + (size_t)s * HEADS);
        float4 ahi = *reinterpret_cast<const float4*>(as1 + (size_t)s * HEADS + 4);
        float lg[HEADS];
        lg[0] = leaky(alo.x + s_adn[0]); lg[1] = leaky(alo.y + s_adn[1]);
        lg[2] = leaky(alo.z + s_adn[2]); lg[3] = leaky(alo.w + s_adn[3]);
        lg[4] = leaky(ahi.x + s_adn[4]); lg[5] = leaky(ahi.y + s_adn[5]);
        lg[6] = leaky(ahi.z + s_adn[6]); lg[7] = leaky(ahi.w + s_adn[7]);
        s_src[i] = s;
#pragma unroll
        for (int h = 0; h < HEADS; h++){ s_w[h][i] = lg[h]; pm[h] = fmaxf(pm[h], lg[h]); }
    }
#pragma unroll
    for (int h = 0; h < HEADS; h++)
#pragma unroll
        for (int off = 32; off >= 1; off >>= 1)
            pm[h] = fmaxf(pm[h], __shfl_down(pm[h], off));
    int wv = t >> 6;
    if ((t & 63) == 0)
#pragma unroll
        for (int h = 0; h < HEADS; h++) s_red[wv][h] = pm[h];
    __syncthreads();
    if (t < HEADS) s_m[t] = fmaxf(s_red[0][t], s_red[1][t]);
    __syncthreads();
    for (int i = t; i < c; i += 128){
#pragma unroll
        for (int h = 0; h < HEADS; h++) s_w[h][i] = __expf(s_w[h][i] - s_m[h]);
    }
    __syncthreads();
    int d0 = 4 * t;
    int h = t >> 4;
    float ac[4][4] = {}, dn[4] = {};
    int i = 0;
    for (; i + 3 < c; i += 4){
#pragma unroll
        for (int u = 0; u < 4; u++){
            float w = s_w[h][i + u]; int s = s_src[i + u];
            uint2 hv = *reinterpret_cast<const uint2*>(h1 + (size_t)s * HID + d0);
            ac[u][0] += w * __uint_as_float(hv.x << 16);
            ac[u][1] += w * __uint_as_float(hv.x & 0xffff0000u);
            ac[u][2] += w * __uint_as_float(hv.y << 16);
            ac[u][3] += w * __uint_as_float(hv.y & 0xffff0000u);
            dn[u] += w;
        }
    }
    for (; i < c; i++){
        float w = s_w[h][i]; int s = s_src[i];
        uint2 hv = *reinterpret_cast<const uint2*>(h1 + (size_t)s * HID + d0);
        ac[0][0] += w * __uint_as_float(hv.x << 16);
        ac[0][1] += w * __uint_as_float(hv.x & 0xffff0000u);
        ac[0][2] += w * __uint_as_float(hv.y << 16);
        ac[0][3] += w * __uint_as_float(hv.y & 0xffff0000u);
        dn[0] += w;
    }
    float den = (dn[0] + dn[1]) + (dn[2] + dn[3]);
    float rd = 1.f / den;
    float4 bv = *reinterpret_cast<const float4*>(b1 + d0);
    float o0 = ((ac[0][0] + ac[1][0]) + (ac[2][0] + ac[3][0])) * rd + bv.x;
    float o1 = ((ac[0][1] + ac[1][1]) + (ac[2][1] + ac[3][1])) * rd + bv.y;
    float o2 = ((ac[0][2] + ac[1][2]) + (ac[2][2] + ac[3][2])) * rd + bv.z;
    float o3 = ((ac[0][3] + ac[1][3]) + (ac[2][3] + ac[3][3])) * rd + bv.w;
    float4 o;
    o.x = o0 > 0.f ? o0 : expm1f(o0);
    o.y = o1 > 0.f ? o1 : expm1f(o1);
    o.z = o2 > 0.f ? o2 : expm1f(o2);
    o.w = o3 > 0.f ? o3 : expm1f(o3);
    *reinterpret_cast<float4*>(&s_row[d0]) = o;
    __syncthreads();
    // fused layer-2 GEMM: 32 cols x 4 K-quarters
    int cc = t & 31, q = t >> 5;
    const float4* wr = reinterpret_cast<const float4*>(W2T + (size_t)cc * HID + q * 128);
    const float4* rr = reinterpret_cast<const float4*>(&s_row[q * 128]);
    float p = 0.f;
#pragma unroll 8
    for (int kk = 0; kk < 32; kk++){
        float4 rv = rr[kk];
        float4 wv = wr[kk];
        p += rv.x * wv.x + rv.y * wv.y + rv.z * wv.z + rv.w * wv.w;
    }
    s_p[q][cc] = p;
    __syncthreads();
    if (t < OUT_DIM){
        float h2c = (s_p[0][t] + s_p[1][t]) + (s_p[2][t] + s_p[3][t]);
        h2[(size_t)n * OUT_DIM + t] = h2c;
        float vs = h2c * a2s[t];
        float vd = h2c * a2d[t];
#pragma unroll
        for (int off = 16; off >= 1; off >>= 1){
            vs += __shfl_xor(vs, off);
            vd += __shfl_xor(vd, off);
        }
        if (t == 0){ vs2[n] = vs; vd2[n] = vd; }
    }
}

// ---------------- layer 2: fused softmax + aggregate + bias ----------------
__launch_bounds__(256)
__global__ void k_agg2(const float* __restrict__ h2, const float* __restrict__ as2,
                       const float* __restrict__ ad2, const int* __restrict__ cnt,
                       const int* __restrict__ esrc,
                       const float* __restrict__ b2, float* __restrict__ out){
    int wv = threadIdx.x >> 6;
    int lane = threadIdx.x & 63;
    int n = blockIdx.x * 4 + wv;
    __shared__ float s_w[4][CAP];
    __shared__ int   s_src[4][CAP];
    int c = cnt[n]; if (c > CAP) c = CAP;
    int beg = n * CAP;
    float adn = ad2[n];
    float pm = -INFINITY;
    for (int i = lane; i < c; i += 64){
        int s = esrc[beg + i];
        float lg = leaky(as2[s] + adn);
        s_src[wv][i] = s; s_w[wv][i] = lg;
        pm = fmaxf(pm, lg);
    }
#pragma unroll
    for (int off = 32; off >= 1; off >>= 1)
        pm = fmaxf(pm, __shfl_xor(pm, off));
    __syncthreads();
    for (int i = lane; i < c; i += 64) s_w[wv][i] = __expf(s_w[wv][i] - pm);
    __syncthreads();
    int d = lane & 31, half = lane >> 5;
    float acc = 0.f, den = 0.f;
    for (int i = half; i < c; i += 2){
        float w = s_w[wv][i]; int s = s_src[wv][i];
        acc += w * h2[(size_t)s * OUT_DIM + d];
        den += w;
    }
    acc += __shfl_xor(acc, 32);
    den += __shfl_xor(den, 32);
    if (lane < OUT_DIM) out[(size_t)n * OUT_DIM + d] = acc / den + b2[d];
}

// ---------------- launch ----------------
extern "C" void kernel_launch(void* const* d_in, const int* in_sizes, int n_in,
                              void* d_out, int out_size, void* d_ws, size_t ws_size,
                              hipStream_t stream){
    const float* x   = (const float*)d_in[0];
    const int*  eidx = (const int*)  d_in[1];
    const float* W1  = (const float*)d_in[2];
    const float* a1s = (const float*)d_in[3];
    const float* a1d = (const float*)d_in[4];
    const float* b1  = (const float*)d_in[5];
    const float* W2  = (const float*)d_in[6];
    const float* a2s = (const float*)d_in[7];
    const float* a2d = (const float*)d_in[8];
    const float* b2  = (const float*)d_in[9];
    float* out = (float*)d_out;

    char* ws = (char*)d_ws;
    size_t off = 0;
    auto alloc = [&](size_t bytes) -> void* {
        void* p = ws + off;
        off += (bytes + 255) & ~(size_t)255;
        return p;
    };
    unsigned short* h1 = (unsigned short*)alloc((size_t)N_NODES * HID * 2);
    unsigned short* Ax = (unsigned short*)alloc((size_t)NRB * RB_SH * 2);   // 5.1 MB
    unsigned short* Bt = (unsigned short*)alloc((size_t)32 * RB_SH * 2);
    float* W2T  = (float*)alloc((size_t)OUT_DIM * HID * 4);
    float* as1  = (float*)alloc((size_t)N_NODES * HEADS * 4);
    float* ad1  = (float*)alloc((size_t)N_NODES * HEADS * 4);
    float* h2   = (float*)alloc((size_t)N_NODES * OUT_DIM * 4);
    float* vs2  = (float*)alloc((size_t)N_NODES * 4);
    float* vd2  = (float*)alloc((size_t)N_NODES * 4);
    int* cnt    = (int*)alloc((size_t)N_NODES * 4);
    int* esrc   = (int*)alloc((size_t)N_NODES * CAP * 4);   // 6.4 MB buckets

    k_pre <<<NRB + PWB + PTB + ZBK, 256, 0, stream>>>(x, W1, W2, cnt, Ax, Bt, W2T);
    k_sg  <<<SCB + NRB, 512, 0, stream>>>(eidx, cnt, esrc, Ax, Bt, a1s, a1d,
                                          h1, as1, ad1);
    k_agg1<<<N_NODES, 128, 0, stream>>>(h1, as1, ad1, cnt, esrc, b1, W2T,
                                        a2s, a2d, h2, vs2, vd2);
    k_agg2<<<N_NODES / 4, 256, 0, stream>>>(h2, vs2, vd2, cnt, esrc, b2, out);
}

// Round 11
// 126.842 us; speedup vs baseline: 1.2288x; 1.2288x over previous
//
#include <hip/hip_runtime.h>
#include <math.h>

#define N_NODES 10000
#define E_EDGES 320000
#define EA      (E_EDGES + N_NODES)   // 330000 with self-loops
#define IN_DIM  128
#define HID     512                    // heads*dhead = 8*64
#define HEADS   8
#define OUT_DIM 32
#define NEG     0.2f
#define CAP     160                    // dst bucket capacity (max degree ~54)
#define N_PAD   10048                  // 628*16
#define NRB     628                    // 16-row blocks
#define RB_SH   4096                   // shorts per 16-row block: 2 seg x 16 chunks x 128

// k_pre block partition (256 threads each)
#define PWB  32                        // prep_w blocks
#define ZBK  40                        // zero cnt blocks
// k_sg block partition (512 threads each)
#define SCB  645                       // scatter: ceil(EA/512)

typedef __attribute__((ext_vector_type(8))) short bf16x8;
typedef __attribute__((ext_vector_type(4))) float f32x4;

__device__ __forceinline__ float leaky(float x){ return x > 0.f ? x : NEG * x; }

__device__ __forceinline__ unsigned short bf16rn(float x){
    unsigned int b = __float_as_uint(x);
    b += 0x7fffu + ((b >> 16) & 1u);
    return (unsigned short)(b >> 16);
}

// ------------- fused prologue: prep_x | prep_w | zero cnt --------
// Fragment-chunk layout per 16-row block: chunk c=(seg*16+kk8);
// dense 16B uint4 stores per thread.
__global__ void k_pre(const float* __restrict__ x, const float* __restrict__ W1,
                      int* __restrict__ cnt,
                      unsigned short* __restrict__ Ax, unsigned short* __restrict__ Bt){
    int b = blockIdx.x, t = threadIdx.x;
    if (b < NRB){
        __shared__ float xs[16 * 132];
        int rb = b;
#pragma unroll
        for (int j = 0; j < 2; j++){
            int idx = t + j * 256;             // 0..511
            int r = idx >> 5, c4 = idx & 31;
            int row = rb * 16 + r;
            float4 v = make_float4(0.f, 0.f, 0.f, 0.f);
            if (row < N_NODES)
                v = *reinterpret_cast<const float4*>(x + (size_t)row * IN_DIM + c4 * 4);
            *reinterpret_cast<float4*>(&xs[r * 132 + c4 * 4]) = v;
        }
        __syncthreads();
        int l15 = t & 15, kk8 = t >> 4;
        unsigned short hi[8], lo[8];
#pragma unroll
        for (int el = 0; el < 8; el++){
            float f = xs[l15 * 132 + kk8 * 8 + el];
            hi[el] = bf16rn(f);
            lo[el] = bf16rn(f - __uint_as_float((unsigned)hi[el] << 16));
        }
        uint4 H, L;
        H.x = hi[0] | ((unsigned)hi[1] << 16); H.y = hi[2] | ((unsigned)hi[3] << 16);
        H.z = hi[4] | ((unsigned)hi[5] << 16); H.w = hi[6] | ((unsigned)hi[7] << 16);
        L.x = lo[0] | ((unsigned)lo[1] << 16); L.y = lo[2] | ((unsigned)lo[3] << 16);
        L.z = lo[4] | ((unsigned)lo[5] << 16); L.w = lo[6] | ((unsigned)lo[7] << 16);
        unsigned short* base = Ax + (size_t)rb * RB_SH;
        *reinterpret_cast<uint4*>(base + (kk8 * 16 + l15) * 8) = H;
        *reinterpret_cast<uint4*>(base + 2048 + (kk8 * 16 + l15) * 8) = L;
    } else if (b < NRB + PWB){
        __shared__ float wsh[128 * 17];
        int nb = b - NRB;
        int j = t & 15, kr = t >> 4;
#pragma unroll
        for (int it = 0; it < 8; it++){
            int k = it * 16 + kr;
            wsh[k * 17 + j] = W1[(size_t)k * HID + nb * 16 + j];
        }
        __syncthreads();
        int l15 = t & 15, kk8 = t >> 4;
        unsigned short hi[8], lo[8];
#pragma unroll
        for (int el = 0; el < 8; el++){
            float f = wsh[(kk8 * 8 + el) * 17 + l15];
            hi[el] = bf16rn(f);
            lo[el] = bf16rn(f - __uint_as_float((unsigned)hi[el] << 16));
        }
        uint4 H, L;
        H.x = hi[0] | ((unsigned)hi[1] << 16); H.y = hi[2] | ((unsigned)hi[3] << 16);
        H.z = hi[4] | ((unsigned)hi[5] << 16); H.w = hi[6] | ((unsigned)hi[7] << 16);
        L.x = lo[0] | ((unsigned)lo[1] << 16); L.y = lo[2] | ((unsigned)lo[3] << 16);
        L.z = lo[4] | ((unsigned)lo[5] << 16); L.w = lo[6] | ((unsigned)lo[7] << 16);
        unsigned short* base = Bt + (size_t)nb * RB_SH;
        *reinterpret_cast<uint4*>(base + (kk8 * 16 + l15) * 8) = H;
        *reinterpret_cast<uint4*>(base + 2048 + (kk8 * 16 + l15) * 8) = L;
    } else {
        int i = (b - NRB - PWB) * 256 + t;
        if (i < N_NODES) cnt[i] = 0;
    }
}

// --------- fused: bucket scatter || layer-1 MFMA GEMM (1 rb x 8 heads/block) ----
// Split GEMM: x@W = xhi·whi + xlo·whi + xhi·wlo (double-bf16, fp32-grade).
__launch_bounds__(512)
__global__ void k_sg(const int* __restrict__ eidx, int* __restrict__ cnt,
                     int* __restrict__ esrc,
                     const unsigned short* __restrict__ Ax,
                     const unsigned short* __restrict__ Bt,
                     const float* __restrict__ a1s, const float* __restrict__ a1d,
                     unsigned short* __restrict__ h1,
                     float* __restrict__ as1, float* __restrict__ ad1){
    if (blockIdx.x < SCB){
        int e = blockIdx.x * 512 + threadIdx.x;
        if (e < EA){
            int d, s;
            if (e < E_EDGES){ s = eidx[e]; d = eidx[E_EDGES + e]; }
            else { s = d = e - E_EDGES; }
            int pos = atomicAdd(&cnt[d], 1);
            if (pos < CAP) esrc[d * CAP + pos] = s;
        }
        return;
    }
    int rb = blockIdx.x - SCB;                 // 0..627
    int by = threadIdx.x >> 6;                 // wave = head
    int lane = threadIdx.x & 63;
    int l15 = lane & 15, grp = lane >> 4;
    int m0 = rb * 16;
    int n0 = by * 64;
    const unsigned short* ap = Ax + (size_t)rb * RB_SH + (size_t)lane * 8;
    bf16x8 a_hi[4], a_lo[4];
#pragma unroll
    for (int ks = 0; ks < 4; ks++){
        a_hi[ks] = *reinterpret_cast<const bf16x8*>(ap + ks * 512);
        a_lo[ks] = *reinterpret_cast<const bf16x8*>(ap + 2048 + ks * 512);
    }
    const unsigned short* bp = Bt + (size_t)(by * 4) * RB_SH + (size_t)lane * 8;
    f32x4 acc[4] = {};
#pragma unroll
    for (int ks = 0; ks < 4; ks++){
#pragma unroll
        for (int ns = 0; ns < 4; ns++){
            const unsigned short* bb = bp + (size_t)ns * RB_SH + ks * 512;
            bf16x8 b_hi = *reinterpret_cast<const bf16x8*>(bb);
            bf16x8 b_lo = *reinterpret_cast<const bf16x8*>(bb + 2048);
            acc[ns] = __builtin_amdgcn_mfma_f32_16x16x32_bf16(a_hi[ks], b_hi, acc[ns], 0, 0, 0);
            acc[ns] = __builtin_amdgcn_mfma_f32_16x16x32_bf16(a_lo[ks], b_hi, acc[ns], 0, 0, 0);
            acc[ns] = __builtin_amdgcn_mfma_f32_16x16x32_bf16(a_hi[ks], b_lo, acc[ns], 0, 0, 0);
        }
    }
    float vs[4] = {0.f, 0.f, 0.f, 0.f}, vd[4] = {0.f, 0.f, 0.f, 0.f};
#pragma unroll
    for (int ns = 0; ns < 4; ns++){
        int c = n0 + ns * 16 + l15;
        float a_s = a1s[c], a_d = a1d[c];
#pragma unroll
        for (int r = 0; r < 4; r++){
            float v = acc[ns][r];
            int rr = m0 + grp * 4 + r;
            if (rr < N_NODES) h1[(size_t)rr * HID + c] = bf16rn(v);
            vs[r] += v * a_s; vd[r] += v * a_d;
        }
    }
#pragma unroll
    for (int r = 0; r < 4; r++){
#pragma unroll
        for (int off = 8; off >= 1; off >>= 1){
            vs[r] += __shfl_xor(vs[r], off);
            vd[r] += __shfl_xor(vd[r], off);
        }
    }
    if (l15 == 0){
#pragma unroll
        for (int r = 0; r < 4; r++){
            int rr = m0 + grp * 4 + r;
            if (rr < N_NODES){ as1[rr * HEADS + by] = vs[r]; ad1[rr * HEADS + by] = vd[r]; }
        }
    }
}

// ---------------- layer 1: fused segment softmax + aggregate + bias + ELU --------
// one block (128 threads) per dst node; R9's proven 48us form (2-way unroll).
__launch_bounds__(128)
__global__ void k_agg1(const unsigned short* __restrict__ h1,
                       const float* __restrict__ as1, const float* __restrict__ ad1,
                       const int* __restrict__ cnt, const int* __restrict__ esrc,
                       const float* __restrict__ b1, float* __restrict__ h1b){
    int n = blockIdx.x;
    int c = cnt[n]; if (c > CAP) c = CAP;
    int beg = n * CAP;
    int t = threadIdx.x;
    __shared__ int   s_src[CAP];
    __shared__ float s_w[HEADS][CAP + 1];   // +1 pad: kills bank conflicts
    __shared__ float s_adn[HEADS];
    __shared__ float s_red[2][HEADS];
    __shared__ float s_m[HEADS];
    if (t < HEADS) s_adn[t] = ad1[n * HEADS + t];
    __syncthreads();
    float pm[HEADS];
#pragma unroll
    for (int h = 0; h < HEADS; h++) pm[h] = -INFINITY;
    for (int i = t; i < c; i += 128){
        int s = esrc[beg + i];
        float4 alo = *reinterpret_cast<const float4*>(as1 + (size_t)s * HEADS);
        float4 ahi = *reinterpret_cast<const float4*>(as1 + (size_t)s * HEADS + 4);
        float lg[HEADS];
        lg[0] = leaky(alo.x + s_adn[0]); lg[1] = leaky(alo.y + s_adn[1]);
        lg[2] = leaky(alo.z + s_adn[2]); lg[3] = leaky(alo.w + s_adn[3]);
        lg[4] = leaky(ahi.x + s_adn[4]); lg[5] = leaky(ahi.y + s_adn[5]);
        lg[6] = leaky(ahi.z + s_adn[6]); lg[7] = leaky(ahi.w + s_adn[7]);
        s_src[i] = s;
#pragma unroll
        for (int h = 0; h < HEADS; h++){ s_w[h][i] = lg[h]; pm[h] = fmaxf(pm[h], lg[h]); }
    }
#pragma unroll
    for (int h = 0; h < HEADS; h++)
#pragma unroll
        for (int off = 32; off >= 1; off >>= 1)
            pm[h] = fmaxf(pm[h], __shfl_down(pm[h], off));
    int wv = t >> 6;
    if ((t & 63) == 0)
#pragma unroll
        for (int h = 0; h < HEADS; h++) s_red[wv][h] = pm[h];
    __syncthreads();
    if (t < HEADS) s_m[t] = fmaxf(s_red[0][t], s_red[1][t]);
    __syncthreads();
    for (int i = t; i < c; i += 128){
#pragma unroll
        for (int h = 0; h < HEADS; h++) s_w[h][i] = __expf(s_w[h][i] - s_m[h]);
    }
    __syncthreads();
    int d0 = 4 * t;
    int h = t >> 4;
    float a0a = 0.f, a1a = 0.f, a2a = 0.f, a3a = 0.f, dena = 0.f;
    float a0b = 0.f, a1b = 0.f, a2b = 0.f, a3b = 0.f, denb = 0.f;
    int i = 0;
    for (; i + 1 < c; i += 2){
        float wa = s_w[h][i];     int sa = s_src[i];
        float wb = s_w[h][i + 1]; int sb = s_src[i + 1];
        uint2 hva = *reinterpret_cast<const uint2*>(h1 + (size_t)sa * HID + d0);
        uint2 hvb = *reinterpret_cast<const uint2*>(h1 + (size_t)sb * HID + d0);
        a0a += wa * __uint_as_float(hva.x << 16);
        a1a += wa * __uint_as_float(hva.x & 0xffff0000u);
        a2a += wa * __uint_as_float(hva.y << 16);
        a3a += wa * __uint_as_float(hva.y & 0xffff0000u);
        dena += wa;
        a0b += wb * __uint_as_float(hvb.x << 16);
        a1b += wb * __uint_as_float(hvb.x & 0xffff0000u);
        a2b += wb * __uint_as_float(hvb.y << 16);
        a3b += wb * __uint_as_float(hvb.y & 0xffff0000u);
        denb += wb;
    }
    if (i < c){
        float w = s_w[h][i]; int s = s_src[i];
        uint2 hv = *reinterpret_cast<const uint2*>(h1 + (size_t)s * HID + d0);
        a0a += w * __uint_as_float(hv.x << 16);
        a1a += w * __uint_as_float(hv.x & 0xffff0000u);
        a2a += w * __uint_as_float(hv.y << 16);
        a3a += w * __uint_as_float(hv.y & 0xffff0000u);
        dena += w;
    }
    float acc0 = a0a + a0b, acc1 = a1a + a1b, acc2 = a2a + a2b, acc3 = a3a + a3b;
    float den = dena + denb;
    float4 bv = *reinterpret_cast<const float4*>(b1 + d0);
    float rd = 1.f / den;
    float o0 = acc0 * rd + bv.x;
    float o1 = acc1 * rd + bv.y;
    float o2 = acc2 * rd + bv.z;
    float o3 = acc3 * rd + bv.w;
    float4 o;
    o.x = o0 > 0.f ? o0 : expm1f(o0);
    o.y = o1 > 0.f ? o1 : expm1f(o1);
    o.z = o2 > 0.f ? o2 : expm1f(o2);
    o.w = o3 > 0.f ? o3 : expm1f(o3);
    *reinterpret_cast<float4*>(h1b + (size_t)n * HID + d0) = o;
}

// ---------------- layer 2: h2 = h1b @ W2 (padded LDS, 4 cols/thread) ------------
// 16 nodes/block amortizes the 64KB W2 read (fusing into agg1 cost 16x W2 traffic).
__launch_bounds__(128)
__global__ void k_gemm2(const float* __restrict__ h1b, const float* __restrict__ W2,
                        const float* __restrict__ a2s, const float* __restrict__ a2d,
                        float* __restrict__ h2, float* __restrict__ as2,
                        float* __restrict__ ad2){
    __shared__ float hs[16 * 516];
    int t = threadIdx.x;
    int n0 = blockIdx.x * 16;
    const float4* src = reinterpret_cast<const float4*>(h1b + (size_t)n0 * HID);
    for (int i = t; i < 2048; i += 128){
        int r = i >> 7, c4 = i & 127;
        *reinterpret_cast<float4*>(&hs[r * 516 + c4 * 4]) = src[i];
    }
    __syncthreads();
    int nl = t >> 3, cg = t & 7, c0 = cg * 4;
    float a0 = 0.f, a1 = 0.f, a2 = 0.f, a3 = 0.f;
#pragma unroll 2
    for (int k4 = 0; k4 < 128; k4++){
        float4 hv = *reinterpret_cast<const float4*>(&hs[nl * 516 + k4 * 4]);
        float4 w0 = *reinterpret_cast<const float4*>(W2 + (k4 * 4 + 0) * OUT_DIM + c0);
        float4 w1 = *reinterpret_cast<const float4*>(W2 + (k4 * 4 + 1) * OUT_DIM + c0);
        float4 w2 = *reinterpret_cast<const float4*>(W2 + (k4 * 4 + 2) * OUT_DIM + c0);
        float4 w3 = *reinterpret_cast<const float4*>(W2 + (k4 * 4 + 3) * OUT_DIM + c0);
        a0 += hv.x * w0.x + hv.y * w1.x + hv.z * w2.x + hv.w * w3.x;
        a1 += hv.x * w0.y + hv.y * w1.y + hv.z * w2.y + hv.w * w3.y;
        a2 += hv.x * w0.z + hv.y * w1.z + hv.z * w2.z + hv.w * w3.z;
        a3 += hv.x * w0.w + hv.y * w1.w + hv.z * w2.w + hv.w * w3.w;
    }
    float4 o; o.x = a0; o.y = a1; o.z = a2; o.w = a3;
    *reinterpret_cast<float4*>(h2 + (size_t)(n0 + nl) * OUT_DIM + c0) = o;
    float4 s4 = *reinterpret_cast<const float4*>(a2s + c0);
    float4 d4 = *reinterpret_cast<const float4*>(a2d + c0);
    float vs = a0 * s4.x + a1 * s4.y + a2 * s4.z + a3 * s4.w;
    float vd = a0 * d4.x + a1 * d4.y + a2 * d4.z + a3 * d4.w;
#pragma unroll
    for (int off = 4; off >= 1; off >>= 1){
        vs += __shfl_xor(vs, off);
        vd += __shfl_xor(vd, off);
    }
    if (cg == 0){ as2[n0 + nl] = vs; ad2[n0 + nl] = vd; }
}

// ---------------- layer 2: fused softmax + aggregate + bias ----------------
__launch_bounds__(256)
__global__ void k_agg2(const float* __restrict__ h2, const float* __restrict__ as2,
                       const float* __restrict__ ad2, const int* __restrict__ cnt,
                       const int* __restrict__ esrc,
                       const float* __restrict__ b2, float* __restrict__ out){
    int wv = threadIdx.x >> 6;
    int lane = threadIdx.x & 63;
    int n = blockIdx.x * 4 + wv;
    __shared__ float s_w[4][CAP];
    __shared__ int   s_src[4][CAP];
    int c = cnt[n]; if (c > CAP) c = CAP;
    int beg = n * CAP;
    float adn = ad2[n];
    float pm = -INFINITY;
    for (int i = lane; i < c; i += 64){
        int s = esrc[beg + i];
        float lg = leaky(as2[s] + adn);
        s_src[wv][i] = s; s_w[wv][i] = lg;
        pm = fmaxf(pm, lg);
    }
#pragma unroll
    for (int off = 32; off >= 1; off >>= 1)
        pm = fmaxf(pm, __shfl_xor(pm, off));
    __syncthreads();
    for (int i = lane; i < c; i += 64) s_w[wv][i] = __expf(s_w[wv][i] - pm);
    __syncthreads();
    int d = lane & 31, half = lane >> 5;
    float acc = 0.f, den = 0.f;
    for (int i = half; i < c; i += 2){
        float w = s_w[wv][i]; int s = s_src[wv][i];
        acc += w * h2[(size_t)s * OUT_DIM + d];
        den += w;
    }
    acc += __shfl_xor(acc, 32);
    den += __shfl_xor(den, 32);
    if (lane < OUT_DIM) out[(size_t)n * OUT_DIM + d] = acc / den + b2[d];
}

// ---------------- launch ----------------
extern "C" void kernel_launch(void* const* d_in, const int* in_sizes, int n_in,
                              void* d_out, int out_size, void* d_ws, size_t ws_size,
                              hipStream_t stream){
    const float* x   = (const float*)d_in[0];
    const int*  eidx = (const int*)  d_in[1];
    const float* W1  = (const float*)d_in[2];
    const float* a1s = (const float*)d_in[3];
    const float* a1d = (const float*)d_in[4];
    const float* b1  = (const float*)d_in[5];
    const float* W2  = (const float*)d_in[6];
    const float* a2s = (const float*)d_in[7];
    const float* a2d = (const float*)d_in[8];
    const float* b2  = (const float*)d_in[9];
    float* out = (float*)d_out;

    char* ws = (char*)d_ws;
    size_t off = 0;
    auto alloc = [&](size_t bytes) -> void* {
        void* p = ws + off;
        off += (bytes + 255) & ~(size_t)255;
        return p;
    };
    unsigned short* h1 = (unsigned short*)alloc((size_t)N_NODES * HID * 2);
    float* h1b  = (float*)alloc((size_t)N_NODES * HID * 4);
    unsigned short* Bt = (unsigned short*)alloc((size_t)32 * RB_SH * 2);
    float* as1  = (float*)alloc((size_t)N_NODES * HEADS * 4);
    float* ad1  = (float*)alloc((size_t)N_NODES * HEADS * 4);
    float* h2   = (float*)alloc((size_t)N_NODES * OUT_DIM * 4);
    float* vs2  = (float*)alloc((size_t)N_NODES * 4);
    float* vd2  = (float*)alloc((size_t)N_NODES * 4);
    int* cnt    = (int*)alloc((size_t)N_NODES * 4);
    int* esrc   = (int*)alloc((size_t)N_NODES * CAP * 4);   // 6.4 MB buckets
    // Ax aliases h1b (5.1 MB < 20.5 MB): k_sg consumes Ax before agg1 writes h1b
    unsigned short* Ax = (unsigned short*)h1b;

    k_pre <<<NRB + PWB + ZBK, 256, 0, stream>>>(x, W1, cnt, Ax, Bt);
    k_sg  <<<SCB + NRB, 512, 0, stream>>>(eidx, cnt, esrc, Ax, Bt, a1s, a1d,
                                          h1, as1, ad1);
    k_agg1<<<N_NODES, 128, 0, stream>>>(h1, as1, ad1, cnt, esrc, b1, h1b);
    k_gemm2<<<N_NODES / 16, 128, 0, stream>>>(h1b, W2, a2s, a2d, h2, vs2, vd2);
    k_agg2<<<N_NODES / 4, 256, 0, stream>>>(h2, vs2, vd2, cnt, esrc, b2, out);
}